// Round 12
// baseline (64.288 us; speedup 1.0000x reference)
//
#include <hip/hip_runtime.h>

// ModalitySpecificLocalSelfAttention — MI355X. f32 I/O, bf16 MFMA internals.
// 3 dispatches:
//   cvt_k: blocks 0..1023 transpose x -> xT bf16 [p][c] (per 4x4 tile, LDS);
//          tail blocks convert weights f32->bf16, scale/bias f32, zero pads.
//   qkv_k: per 4x4 tile: q=conv2(conv1(x)), k=conv2(conv1(x)), v=conv(x);
//          A-frags straight from global xT (no x staging, 3 barriers);
//          q -> [p][c]; k,v -> padded [134][134][128] global.
//   att_k: q/xT frags prefetched to regs; stage K halo [100][136] -> S=Q*K^T
//          via MFMA on all 4 waves -> masked softmax (P f32 LDS) -> V halo
//          over same buffer -> PV (VALU) -> final conv -> f32 [c][p] out.

typedef short short8 __attribute__((ext_vector_type(8)));
typedef short short4v __attribute__((ext_vector_type(4)));
typedef float f32x4 __attribute__((ext_vector_type(4)));

#define HW_PIX 16384   // H*W
#define CH 128
#define PADW 134       // 128 + 2*3
#define PSLOT (134 * 134 * 128)

// ws layout in 16-bit units
#define WQ1_OFF 0
#define WQ2_OFF 16384
#define WK1_OFF 32768
#define WK2_OFF 49152
#define WV_OFF  65536
#define WO_OFF  81920            // 128x256
#define SB_OFF  114688           // 1536 f32 (3072 shorts)
#define TQ_OFF  117760           // q [p][c]
#define XT_OFF  (TQ_OFF + 2097152)
#define KP_OFF  (XT_OFF + 2097152)
#define VP_OFF  (KP_OFF + PSLOT)

static __device__ __forceinline__ float bf2f(unsigned short u) {
    union { unsigned int i; float f; } c; c.i = ((unsigned int)u) << 16; return c.f;
}
static __device__ __forceinline__ unsigned short f2bf(float f) {
    union { unsigned int i; float f; } c; c.f = f;
    unsigned int x = c.i;
    return (unsigned short)((x + 0x7fffu + ((x >> 16) & 1u)) >> 16);  // RNE
}

// ---- cvt: x transpose (blocks 0..1023) + weights/sb/pads (tail blocks) ----
struct CvtArgs { const float* w[6]; const float* sb[12]; };

__global__ __launch_bounds__(256)
void cvt_k(CvtArgs a, const float* __restrict__ x, short* __restrict__ ws)
{
    __shared__ short xb[16 * 136];
    const int tid = threadIdx.x;
    const int bid = blockIdx.x;

    if (bid < 1024) {                        // xT tile: f32 [c][p] -> bf16 [p][c]
        const int tr = bid >> 5, tc = bid & 31;
        const int h0 = tr * 4, w0 = tc * 4;
        #pragma unroll
        for (int pass = 0; pass < 2; ++pass) {
            const int u = tid + pass * 256;             // 512 units
            const int c = u >> 2, r = u & 3;
            f32x4 v = *(const f32x4*)(x + c * HW_PIX + (h0 + r) * 128 + w0);
            #pragma unroll
            for (int j = 0; j < 4; ++j) xb[(r * 4 + j) * 136 + c] = (short)f2bf(v[j]);
        }
        __syncthreads();
        const int px = tid >> 4, c8 = tid & 15;
        const int p_img = (h0 + (px >> 2)) * 128 + w0 + (px & 3);
        *(short8*)(ws + XT_OFF + p_img * CH + c8 * 8) =
            *(const short8*)(xb + px * 136 + c8 * 8);
        return;
    }

    const int u = (bid - 1024) * 256 + tid;  // 75 tail blocks = 19200 units
    if (u < 14336) {                                 // 114688 weight elems
        const int s0 = u * 8;
        const int seg = (s0 < 81920) ? (s0 >> 14) : 5;
        const int base = (seg < 5) ? (seg << 14) : 81920;
        const float* fp = a.w[seg] + (s0 - base);
        short8 o;
        #pragma unroll
        for (int j = 0; j < 8; ++j) o[j] = (short)f2bf(fp[j]);
        *(short8*)(ws + s0) = o;
    } else if (u < 15872) {                          // 1536 scale/bias floats
        const int idx = u - 14336;
        ((float*)(ws + SB_OFF))[idx] = a.sb[idx >> 7][idx & 127];
    } else if (u < 15872 + 3144) {                   // zero pad pixels of k,v
        const int idx = u - 15872;
        const int buf = idx / 1572;                  // 0 = k, 1 = v
        const int e   = idx % 1572;
        int row, col;
        if (e < 402)      { row = e / PADW;          col = e % PADW; }
        else if (e < 804) { row = 131 + (e - 402) / PADW; col = (e - 402) % PADW; }
        else { const int r = e - 804; row = 3 + r / 6; const int c = r % 6;
               col = (c < 3) ? c : (128 + c); }
        short* p = ws + (buf ? VP_OFF : KP_OFF) + (row * PADW + col) * CH;
        const short8 z = {0, 0, 0, 0, 0, 0, 0, 0};
        #pragma unroll
        for (int j = 0; j < 16; ++j) *(short8*)(p + j * 8) = z;
    }
}

// ---- q/k/v projections over 4x4-px tiles; A-frags from global xT ----
__global__ __launch_bounds__(256)
void qkv_k(short* __restrict__ ws)
{
    const float* sb = (const float*)(ws + SB_OFF);
    const int tid = threadIdx.x;
    const int bid = blockIdx.x;
    const int t   = (bid & 7) * 128 + (bid >> 3);   // XCD bands
    const int tr = t >> 5, tc = t & 31;
    const int h0 = tr * 4, w0 = tc * 4;

    const int l16 = tid & 15;
    const int g   = (tid & 63) >> 4;
    const int wv  = tid >> 6;
    const int o0  = wv * 32;
    const int ap_img = (h0 + (l16 >> 2)) * 128 + w0 + (l16 & 3);   // A-row pixel

    __shared__ short tileQ[16 * 136];
    __shared__ short tileK[16 * 136];
    __shared__ short tileV[16 * 136];

    // x A-fragments straight from xT (L2-resident, 16B/lane)
    short8 xa[4];
    #pragma unroll
    for (int kk = 0; kk < 4; ++kk)
        xa[kk] = *(const short8*)(ws + XT_OFF + ap_img * CH + kk * 32 + g * 8);

    const f32x4 z = {0.f, 0.f, 0.f, 0.f};
    f32x4 acc[2];

    #define GEMM1(WOFF, SIDX, TILE)                                              \
    {                                                                            \
        acc[0] = z; acc[1] = z;                                                  \
        _Pragma("unroll")                                                        \
        for (int kk = 0; kk < 4; ++kk) {                                         \
            _Pragma("unroll")                                                    \
            for (int nt = 0; nt < 2; ++nt) {                                     \
                short8 bv = *(const short8*)(ws + WOFF +                         \
                    (o0 + nt * 16 + l16) * 128 + kk * 32 + g * 8);               \
                acc[nt] = __builtin_amdgcn_mfma_f32_16x16x32_bf16(xa[kk], bv, acc[nt], 0, 0, 0); \
            }                                                                    \
        }                                                                        \
        _Pragma("unroll")                                                        \
        for (int nt = 0; nt < 2; ++nt) {                                         \
            const int o = o0 + nt * 16 + l16;                                    \
            const float sf = sb[(SIDX) * 128 + o], bf = sb[(SIDX + 1) * 128 + o];\
            _Pragma("unroll")                                                    \
            for (int i = 0; i < 4; ++i) {                                        \
                const float vl = fmaxf(acc[nt][i] * sf + bf, 0.f);               \
                TILE[(g * 4 + i) * 136 + o] = (short)f2bf(vl);                   \
            }                                                                    \
        }                                                                        \
    }
    GEMM1(WQ1_OFF, 0, tileQ)
    GEMM1(WK1_OFF, 4, tileK)
    GEMM1(WV_OFF,  8, tileV)
    #undef GEMM1

    __syncthreads();

    // stage 2: q2 over tileQ, k2 over tileK
    short8 lf[4];
    f32x4 accQ[2], accK[2];
    accQ[0] = z; accQ[1] = z; accK[0] = z; accK[1] = z;
    #pragma unroll
    for (int kk = 0; kk < 4; ++kk) lf[kk] = *(const short8*)(tileQ + l16 * 136 + kk * 32 + g * 8);
    #pragma unroll
    for (int kk = 0; kk < 4; ++kk) {
        #pragma unroll
        for (int nt = 0; nt < 2; ++nt) {
            short8 bv = *(const short8*)(ws + WQ2_OFF + (o0 + nt * 16 + l16) * 128 + kk * 32 + g * 8);
            accQ[nt] = __builtin_amdgcn_mfma_f32_16x16x32_bf16(lf[kk], bv, accQ[nt], 0, 0, 0);
        }
    }
    #pragma unroll
    for (int kk = 0; kk < 4; ++kk) lf[kk] = *(const short8*)(tileK + l16 * 136 + kk * 32 + g * 8);
    #pragma unroll
    for (int kk = 0; kk < 4; ++kk) {
        #pragma unroll
        for (int nt = 0; nt < 2; ++nt) {
            short8 bv = *(const short8*)(ws + WK2_OFF + (o0 + nt * 16 + l16) * 128 + kk * 32 + g * 8);
            accK[nt] = __builtin_amdgcn_mfma_f32_16x16x32_bf16(lf[kk], bv, accK[nt], 0, 0, 0);
        }
    }
    __syncthreads();   // q1/k1 reads done before overwrite

    #pragma unroll
    for (int nt = 0; nt < 2; ++nt) {
        const int o = o0 + nt * 16 + l16;
        const float sfq = sb[2 * 128 + o], bfq = sb[3 * 128 + o];
        const float sfk = sb[6 * 128 + o], bfk = sb[7 * 128 + o];
        #pragma unroll
        for (int i = 0; i < 4; ++i) {
            tileQ[(g * 4 + i) * 136 + o] = (short)f2bf(fmaxf(accQ[nt][i] * sfq + bfq, 0.f));
            tileK[(g * 4 + i) * 136 + o] = (short)f2bf(fmaxf(accK[nt][i] * sfk + bfk, 0.f));
        }
    }
    __syncthreads();

    // stores: q -> TQ [p][c]; k,v -> padded global
    {
        const int px = tid >> 4, c8 = tid & 15;
        const int soff = px * 136 + c8 * 8;
        const int p_img = (h0 + (px >> 2)) * 128 + w0 + (px & 3);
        const int pr = h0 + (px >> 2) + 3, pc = w0 + (px & 3) + 3;
        const int doff = (pr * PADW + pc) * CH + c8 * 8;
        *(short8*)(ws + TQ_OFF + p_img * CH + c8 * 8) = *(const short8*)(tileQ + soff);
        *(short8*)(ws + KP_OFF + doff) = *(const short8*)(tileK + soff);
        *(short8*)(ws + VP_OFF + doff) = *(const short8*)(tileV + soff);
    }
}

// ---- attention (all-wave MFMA QK) + final conv over 4x4-px tiles ----
__global__ __launch_bounds__(256)
void att_k(const short* __restrict__ ws, float* __restrict__ out)
{
    const float* sb = (const float*)(ws + SB_OFF);

    __shared__ __align__(16) short halKV[100 * 136];  // K halo, then V halo, then outT
    __shared__ __align__(16) float Pf[16 * 100];      // raw S -> exp(P); attT aliases
    __shared__ float rzL[16];

    short* attT = (short*)Pf;            // [16][136] (4352 B < 6400 B) after sync
    short* outT = halKV;                 // [128][24] in final phase

    const int tid = threadIdx.x;
    const int bid = blockIdx.x;
    const int t   = (bid & 7) * 128 + (bid >> 3);
    const int tr = t >> 5, tc = t & 31;
    const int h0 = tr * 4, w0 = tc * 4;

    const int l16 = tid & 15;
    const int g   = (tid & 63) >> 4;
    const int wv  = tid >> 6;
    const f32x4 z4 = {0.f, 0.f, 0.f, 0.f};

    const int ap_img = (h0 + (l16 >> 2)) * 128 + w0 + (l16 & 3);   // A-row pixel

    // prefetch q and xT A-fragments (all global deps issue before any barrier)
    short8 af[4], xf[4];
    #pragma unroll
    for (int kk = 0; kk < 4; ++kk) {
        af[kk] = *(const short8*)(ws + TQ_OFF + ap_img * CH + kk * 32 + g * 8);
        xf[kk] = *(const short8*)(ws + XT_OFF + ap_img * CH + kk * 32 + g * 8);
    }

    // ---- stage K halo [100][136] ----
    for (int u = tid; u < 1600; u += 256) {
        const int di = u / 160, rem = u - di * 160;
        const int j = rem >> 4, c8 = rem & 15;
        *(short8*)(halKV + (di * 10 + j) * 136 + c8 * 8) =
            *(const short8*)(ws + KP_OFF + ((h0 + di) * PADW + (w0 + j)) * CH + c8 * 8);
    }
    __syncthreads();

    // ---- S = Q * K^T via MFMA, n-tiles split across all 4 waves ----
    #pragma unroll
    for (int s = 0; s < 2; ++s) {
        const int nt = wv + s * 4;
        if (nt < 7) {
            f32x4 sa = z4;
            #pragma unroll
            for (int kk = 0; kk < 4; ++kk) {
                short8 bv = *(const short8*)(halKV + (nt * 16 + l16) * 136 + kk * 32 + g * 8);
                sa = __builtin_amdgcn_mfma_f32_16x16x32_bf16(af[kk], bv, sa, 0, 0, 0);
            }
            const int col = nt * 16 + l16;
            if (col < 100) {
                #pragma unroll
                for (int i = 0; i < 4; ++i)
                    Pf[(g * 4 + i) * 100 + col] = sa[i];
            }
        }
    }
    __syncthreads();

    // ---- parallel masked softmax: 16 px-groups x 16 lanes ----
    const int px = tid >> 4;
    const int r = px >> 2, cl = px & 3;
    {
        float vals[7];
        float mx = -3.0e38f;
        #pragma unroll
        for (int n = 0; n < 7; ++n) {
            const int hp = n * 16 + l16;
            float v = -3.0e38f;
            if (hp < 100) {
                const int hr = hp / 10, hc = hp - (hp / 10) * 10;
                if ((unsigned)(hr - r) < 7u && (unsigned)(hc - cl) < 7u)
                    v = Pf[px * 100 + hp];       // image-OOB taps are S=0 (k=0)
            }
            vals[n] = v; mx = fmaxf(mx, v);
        }
        mx = fmaxf(mx, __shfl_xor(mx, 1, 16));
        mx = fmaxf(mx, __shfl_xor(mx, 2, 16));
        mx = fmaxf(mx, __shfl_xor(mx, 4, 16));
        mx = fmaxf(mx, __shfl_xor(mx, 8, 16));
        float zs = 0.f;
        #pragma unroll
        for (int n = 0; n < 7; ++n) {
            const int hp = n * 16 + l16;
            const float ev = (vals[n] > -1.0e37f) ? __expf(vals[n] - mx) : 0.f;
            zs += ev;
            if (hp < 100) Pf[px * 100 + hp] = ev;
        }
        zs += __shfl_xor(zs, 1, 16);
        zs += __shfl_xor(zs, 2, 16);
        zs += __shfl_xor(zs, 4, 16);
        zs += __shfl_xor(zs, 8, 16);
        if (l16 == 0) rzL[px] = 1.0f / zs;
    }
    __syncthreads();

    // ---- stage V halo over the same buffer ----
    for (int u = tid; u < 1600; u += 256) {
        const int di = u / 160, rem = u - di * 160;
        const int j = rem >> 4, c8 = rem & 15;
        *(short8*)(halKV + (di * 10 + j) * 136 + c8 * 8) =
            *(const short8*)(ws + VP_OFF + ((h0 + di) * PADW + (w0 + j)) * CH + c8 * 8);
    }
    __syncthreads();

    // ---- PV (VALU, broadcast P) ----
    float of[8];
    {
        const int cb = l16 * 8;
        #pragma unroll
        for (int j = 0; j < 8; ++j) of[j] = 0.f;
        #pragma unroll
        for (int off = 0; off < 49; ++off) {
            const int di = off / 7, dj = off % 7;
            const int hp = (r + di) * 10 + cl + dj;
            const float ev = Pf[px * 100 + hp];
            short8 vv = *(const short8*)(halKV + hp * 136 + cb);
            #pragma unroll
            for (int j = 0; j < 8; ++j) of[j] += ev * bf2f((unsigned short)vv[j]);
        }
        const float rz = rzL[px];
        #pragma unroll
        for (int j = 0; j < 8; ++j) of[j] *= rz;
    }
    __syncthreads();   // all Pf reads done before attT (alias) writes

    {
        const int cb = l16 * 8;
        short8 ov;
        #pragma unroll
        for (int j = 0; j < 8; ++j) ov[j] = (short)f2bf(of[j]);
        *(short8*)(attT + px * 136 + cb) = ov;
    }
    __syncthreads();

    // ---- final conv: 16px x 128och x K=256 (attT | xf regs) ----
    const int o0 = wv * 32;
    f32x4 fac[2];
    fac[0] = z4; fac[1] = z4;
    #pragma unroll
    for (int kk = 0; kk < 8; ++kk) {
        const int kbase = kk * 32 + g * 8;
        short8 av;
        if (kk < 4) av = *(const short8*)(attT + l16 * 136 + kbase);
        else        av = xf[kk - 4];
        #pragma unroll
        for (int nt = 0; nt < 2; ++nt) {
            short8 bv = *(const short8*)(ws + WO_OFF + (o0 + nt * 16 + l16) * 256 + kbase);
            fac[nt] = __builtin_amdgcn_mfma_f32_16x16x32_bf16(av, bv, fac[nt], 0, 0, 0);
        }
    }
    {
        const float* s  = sb + 10 * 128;
        const float* bb = sb + 11 * 128;
        #pragma unroll
        for (int nt = 0; nt < 2; ++nt) {
            const int o = o0 + nt * 16 + l16;
            const float sf = s[o], bf = bb[o];
            #pragma unroll
            for (int i = 0; i < 4; ++i)
                outT[o * 24 + g * 4 + i] = (short)f2bf(fac[nt][i] * sf + bf);  // no ReLU
        }
    }
    __syncthreads();
    #pragma unroll
    for (int pass = 0; pass < 2; ++pass) {
        const int u = tid + pass * 256;              // 512 units of 4 f32
        const int c = u >> 2, rr = u & 3;
        short4v sv = *(const short4v*)(outT + c * 24 + rr * 4);
        f32x4 fv;
        #pragma unroll
        for (int j = 0; j < 4; ++j) fv[j] = bf2f((unsigned short)sv[j]);
        *(f32x4*)(out + c * HW_PIX + (h0 + rr) * 128 + w0) = fv;
    }
}

extern "C" void kernel_launch(void* const* d_in, const int* in_sizes, int n_in,
                              void* d_out, int out_size, void* d_ws, size_t ws_size,
                              hipStream_t stream)
{
    const float* x = (const float*)d_in[0];
    short* ws = (short*)d_ws;

    CvtArgs ca;
    ca.w[0] = (const float*)d_in[1];   // w_q1
    ca.w[1] = (const float*)d_in[4];   // w_q2
    ca.w[2] = (const float*)d_in[7];   // w_k1
    ca.w[3] = (const float*)d_in[10];  // w_k2
    ca.w[4] = (const float*)d_in[13];  // w_v
    ca.w[5] = (const float*)d_in[16];  // w_o
    ca.sb[0]  = (const float*)d_in[2];  ca.sb[1]  = (const float*)d_in[3];
    ca.sb[2]  = (const float*)d_in[5];  ca.sb[3]  = (const float*)d_in[6];
    ca.sb[4]  = (const float*)d_in[8];  ca.sb[5]  = (const float*)d_in[9];
    ca.sb[6]  = (const float*)d_in[11]; ca.sb[7]  = (const float*)d_in[12];
    ca.sb[8]  = (const float*)d_in[14]; ca.sb[9]  = (const float*)d_in[15];
    ca.sb[10] = (const float*)d_in[17]; ca.sb[11] = (const float*)d_in[18];

    cvt_k<<<dim3(1099), dim3(256), 0, stream>>>(ca, x, ws);
    qkv_k<<<dim3(1024), dim3(256), 0, stream>>>(ws);
    att_k<<<dim3(1024), dim3(256), 0, stream>>>(ws, (float*)d_out);
}

// Round 13
// 55.744 us; speedup vs baseline: 1.1533x; 1.1533x over previous
//
#include <hip/hip_runtime.h>

// ModalitySpecificLocalSelfAttention — MI355X. f32 I/O, bf16 MFMA internals.
// 3 dispatches (round-11 structure; att_k barrier chain shortened 7->5):
//   cvt_k: weights f32->bf16, scale/bias f32, zero k/v pad pixels.
//   qkv_k: per 4x4 tile: stage x (f32 coalesced -> LDS bf16), q=conv2(conv1),
//          k=conv2(conv1), v=conv; q,xT -> [p][c]; k,v -> padded global.
//   att_k: stage K halo [100][136] -> S=Q*K^T via MFMA (all 4 waves) ->
//          {V-halo staging overlapped with masked softmax} -> PV (VALU) ->
//          final conv (attB | xf regs) -> f32 [c][p] out.

typedef short short8 __attribute__((ext_vector_type(8)));
typedef short short4v __attribute__((ext_vector_type(4)));
typedef float f32x4 __attribute__((ext_vector_type(4)));

#define HW_PIX 16384   // H*W
#define CH 128
#define PADW 134       // 128 + 2*3
#define PSLOT (134 * 134 * 128)

// ws layout in 16-bit units
#define WQ1_OFF 0
#define WQ2_OFF 16384
#define WK1_OFF 32768
#define WK2_OFF 49152
#define WV_OFF  65536
#define WO_OFF  81920            // 128x256
#define SB_OFF  114688           // 1536 f32 (3072 shorts)
#define TQ_OFF  117760           // q [p][c]
#define XT_OFF  (TQ_OFF + 2097152)
#define KP_OFF  (XT_OFF + 2097152)
#define VP_OFF  (KP_OFF + PSLOT)

static __device__ __forceinline__ float bf2f(unsigned short u) {
    union { unsigned int i; float f; } c; c.i = ((unsigned int)u) << 16; return c.f;
}
static __device__ __forceinline__ unsigned short f2bf(float f) {
    union { unsigned int i; float f; } c; c.f = f;
    unsigned int x = c.i;
    return (unsigned short)((x + 0x7fffu + ((x >> 16) & 1u)) >> 16);  // RNE
}

// ---- weights/scale-bias conversion + k/v pad zeroing ----
struct CvtArgs { const float* w[6]; const float* sb[12]; };

__global__ __launch_bounds__(256)
void cvt_k(CvtArgs a, short* __restrict__ ws)
{
    const int u = blockIdx.x * 256 + threadIdx.x;   // 75 blocks = 19200 units
    if (u < 14336) {                                 // 114688 weight elems
        const int s0 = u * 8;
        const int seg = (s0 < 81920) ? (s0 >> 14) : 5;
        const int base = (seg < 5) ? (seg << 14) : 81920;
        const float* fp = a.w[seg] + (s0 - base);
        short8 o;
        #pragma unroll
        for (int j = 0; j < 8; ++j) o[j] = (short)f2bf(fp[j]);
        *(short8*)(ws + s0) = o;
    } else if (u < 15872) {                          // 1536 scale/bias floats
        const int idx = u - 14336;
        ((float*)(ws + SB_OFF))[idx] = a.sb[idx >> 7][idx & 127];
    } else if (u < 15872 + 3144) {                   // zero pad pixels of k,v
        const int idx = u - 15872;
        const int buf = idx / 1572;                  // 0 = k, 1 = v
        const int e   = idx % 1572;
        int row, col;
        if (e < 402)      { row = e / PADW;          col = e % PADW; }
        else if (e < 804) { row = 131 + (e - 402) / PADW; col = (e - 402) % PADW; }
        else { const int r = e - 804; row = 3 + r / 6; const int c = r % 6;
               col = (c < 3) ? c : (128 + c); }
        short* p = ws + (buf ? VP_OFF : KP_OFF) + (row * PADW + col) * CH;
        const short8 z = {0, 0, 0, 0, 0, 0, 0, 0};
        #pragma unroll
        for (int j = 0; j < 16; ++j) *(short8*)(p + j * 8) = z;
    }
}

// ---- q/k/v projections over 4x4-px tiles (round-11 verbatim) ----
__global__ __launch_bounds__(256)
void qkv_k(const float* __restrict__ x, short* __restrict__ ws)
{
    const float* sb = (const float*)(ws + SB_OFF);
    const int tid = threadIdx.x;
    const int bid = blockIdx.x;
    const int t   = (bid & 7) * 128 + (bid >> 3);   // XCD bands
    const int tr = t >> 5, tc = t & 31;
    const int h0 = tr * 4, w0 = tc * 4;

    const int l16 = tid & 15;
    const int g   = (tid & 63) >> 4;
    const int wv  = tid >> 6;
    const int o0  = wv * 32;

    __shared__ short xb[16 * 136];
    __shared__ short tileQ[16 * 136];
    __shared__ short tileK[16 * 136];
    __shared__ short tileV[16 * 136];

    // stage x tile: f32 [c][p] coalesced -> bf16 xb[px][c], px = r*4+cl
    #pragma unroll
    for (int pass = 0; pass < 2; ++pass) {
        const int u = tid + pass * 256;             // 512 units
        const int c = u >> 2, r = u & 3;
        f32x4 v = *(const f32x4*)(x + c * HW_PIX + (h0 + r) * 128 + w0);
        #pragma unroll
        for (int j = 0; j < 4; ++j) xb[(r * 4 + j) * 136 + c] = (short)f2bf(v[j]);
    }
    __syncthreads();

    // xT -> global [p][c]
    {
        const int px = tid >> 4, c8 = tid & 15;
        const int p_img = (h0 + (px >> 2)) * 128 + w0 + (px & 3);
        *(short8*)(ws + XT_OFF + p_img * CH + c8 * 8) =
            *(const short8*)(xb + px * 136 + c8 * 8);
    }

    short8 xa[4];
    #pragma unroll
    for (int kk = 0; kk < 4; ++kk)
        xa[kk] = *(const short8*)(xb + l16 * 136 + kk * 32 + g * 8);

    const f32x4 z = {0.f, 0.f, 0.f, 0.f};
    f32x4 acc[2];

    #define GEMM1(WOFF, SIDX, TILE)                                              \
    {                                                                            \
        acc[0] = z; acc[1] = z;                                                  \
        _Pragma("unroll")                                                        \
        for (int kk = 0; kk < 4; ++kk) {                                         \
            _Pragma("unroll")                                                    \
            for (int nt = 0; nt < 2; ++nt) {                                     \
                short8 bv = *(const short8*)(ws + WOFF +                         \
                    (o0 + nt * 16 + l16) * 128 + kk * 32 + g * 8);               \
                acc[nt] = __builtin_amdgcn_mfma_f32_16x16x32_bf16(xa[kk], bv, acc[nt], 0, 0, 0); \
            }                                                                    \
        }                                                                        \
        _Pragma("unroll")                                                        \
        for (int nt = 0; nt < 2; ++nt) {                                         \
            const int o = o0 + nt * 16 + l16;                                    \
            const float sf = sb[(SIDX) * 128 + o], bf = sb[(SIDX + 1) * 128 + o];\
            _Pragma("unroll")                                                    \
            for (int i = 0; i < 4; ++i) {                                        \
                const float vl = fmaxf(acc[nt][i] * sf + bf, 0.f);               \
                TILE[(g * 4 + i) * 136 + o] = (short)f2bf(vl);                   \
            }                                                                    \
        }                                                                        \
    }
    GEMM1(WQ1_OFF, 0, tileQ)
    GEMM1(WK1_OFF, 4, tileK)
    GEMM1(WV_OFF,  8, tileV)
    #undef GEMM1

    __syncthreads();

    // stage 2: q2 over tileQ, k2 over tileK
    short8 lf[4];
    f32x4 accQ[2], accK[2];
    accQ[0] = z; accQ[1] = z; accK[0] = z; accK[1] = z;
    #pragma unroll
    for (int kk = 0; kk < 4; ++kk) lf[kk] = *(const short8*)(tileQ + l16 * 136 + kk * 32 + g * 8);
    #pragma unroll
    for (int kk = 0; kk < 4; ++kk) {
        #pragma unroll
        for (int nt = 0; nt < 2; ++nt) {
            short8 bv = *(const short8*)(ws + WQ2_OFF + (o0 + nt * 16 + l16) * 128 + kk * 32 + g * 8);
            accQ[nt] = __builtin_amdgcn_mfma_f32_16x16x32_bf16(lf[kk], bv, accQ[nt], 0, 0, 0);
        }
    }
    #pragma unroll
    for (int kk = 0; kk < 4; ++kk) lf[kk] = *(const short8*)(tileK + l16 * 136 + kk * 32 + g * 8);
    #pragma unroll
    for (int kk = 0; kk < 4; ++kk) {
        #pragma unroll
        for (int nt = 0; nt < 2; ++nt) {
            short8 bv = *(const short8*)(ws + WK2_OFF + (o0 + nt * 16 + l16) * 128 + kk * 32 + g * 8);
            accK[nt] = __builtin_amdgcn_mfma_f32_16x16x32_bf16(lf[kk], bv, accK[nt], 0, 0, 0);
        }
    }
    __syncthreads();   // q1/k1 reads done before overwrite

    #pragma unroll
    for (int nt = 0; nt < 2; ++nt) {
        const int o = o0 + nt * 16 + l16;
        const float sfq = sb[2 * 128 + o], bfq = sb[3 * 128 + o];
        const float sfk = sb[6 * 128 + o], bfk = sb[7 * 128 + o];
        #pragma unroll
        for (int i = 0; i < 4; ++i) {
            tileQ[(g * 4 + i) * 136 + o] = (short)f2bf(fmaxf(accQ[nt][i] * sfq + bfq, 0.f));
            tileK[(g * 4 + i) * 136 + o] = (short)f2bf(fmaxf(accK[nt][i] * sfk + bfk, 0.f));
        }
    }
    __syncthreads();

    // stores: q -> TQ [p][c]; k,v -> padded global
    {
        const int px = tid >> 4, c8 = tid & 15;
        const int soff = px * 136 + c8 * 8;
        const int p_img = (h0 + (px >> 2)) * 128 + w0 + (px & 3);
        const int pr = h0 + (px >> 2) + 3, pc = w0 + (px & 3) + 3;
        const int doff = (pr * PADW + pc) * CH + c8 * 8;
        *(short8*)(ws + TQ_OFF + p_img * CH + c8 * 8) = *(const short8*)(tileQ + soff);
        *(short8*)(ws + KP_OFF + doff) = *(const short8*)(tileK + soff);
        *(short8*)(ws + VP_OFF + doff) = *(const short8*)(tileV + soff);
    }
}

// ---- attention (all-wave MFMA QK) + final conv; 5 barriers ----
__global__ __launch_bounds__(256, 4)
void att_k(const short* __restrict__ ws, float* __restrict__ out)
{
    const float* sb = (const float*)(ws + SB_OFF);

    __shared__ __align__(16) short halKV[100 * 136];  // K halo -> V halo -> outT
    __shared__ __align__(16) float Pf[16 * 100];      // raw S -> exp(P)
    __shared__ __align__(16) short attB[16 * 136];    // attention out tile
    __shared__ float rzL[16];

    short* outT = halKV;                 // [128][24] in final phase

    const int tid = threadIdx.x;
    const int bid = blockIdx.x;
    const int t   = (bid & 7) * 128 + (bid >> 3);
    const int tr = t >> 5, tc = t & 31;
    const int h0 = tr * 4, w0 = tc * 4;

    const int l16 = tid & 15;
    const int g   = (tid & 63) >> 4;
    const int wv  = tid >> 6;
    const f32x4 z4 = {0.f, 0.f, 0.f, 0.f};

    const int ap_img = (h0 + (l16 >> 2)) * 128 + w0 + (l16 & 3);   // A-row pixel

    // prefetch q and xT A-fragments (global deps issue before any barrier)
    short8 af[4], xf[4];
    #pragma unroll
    for (int kk = 0; kk < 4; ++kk) {
        af[kk] = *(const short8*)(ws + TQ_OFF + ap_img * CH + kk * 32 + g * 8);
        xf[kk] = *(const short8*)(ws + XT_OFF + ap_img * CH + kk * 32 + g * 8);
    }

    // ---- stage K halo [100][136] ----
    for (int u = tid; u < 1600; u += 256) {
        const int di = u / 160, rem = u - di * 160;
        const int j = rem >> 4, c8 = rem & 15;
        *(short8*)(halKV + (di * 10 + j) * 136 + c8 * 8) =
            *(const short8*)(ws + KP_OFF + ((h0 + di) * PADW + (w0 + j)) * CH + c8 * 8);
    }
    __syncthreads();                                           // B1

    // ---- S = Q * K^T via MFMA, n-tiles split across all 4 waves ----
    #pragma unroll
    for (int s = 0; s < 2; ++s) {
        const int nt = wv + s * 4;
        if (nt < 7) {
            f32x4 sa = z4;
            #pragma unroll
            for (int kk = 0; kk < 4; ++kk) {
                short8 bv = *(const short8*)(halKV + (nt * 16 + l16) * 136 + kk * 32 + g * 8);
                sa = __builtin_amdgcn_mfma_f32_16x16x32_bf16(af[kk], bv, sa, 0, 0, 0);
            }
            const int col = nt * 16 + l16;
            if (col < 100) {
                #pragma unroll
                for (int i = 0; i < 4; ++i)
                    Pf[(g * 4 + i) * 100 + col] = sa[i];
            }
        }
    }
    __syncthreads();                                           // B2 (K reads done)

    // ---- V-halo staging (overwrites halKV) overlapped with softmax ----
    for (int u = tid; u < 1600; u += 256) {
        const int di = u / 160, rem = u - di * 160;
        const int j = rem >> 4, c8 = rem & 15;
        *(short8*)(halKV + (di * 10 + j) * 136 + c8 * 8) =
            *(const short8*)(ws + VP_OFF + ((h0 + di) * PADW + (w0 + j)) * CH + c8 * 8);
    }

    // parallel masked softmax (independent of halKV): 16 px-groups x 16 lanes
    const int px = tid >> 4;
    const int r = px >> 2, cl = px & 3;
    {
        float vals[7];
        float mx = -3.0e38f;
        #pragma unroll
        for (int n = 0; n < 7; ++n) {
            const int hp = n * 16 + l16;
            float v = -3.0e38f;
            if (hp < 100) {
                const int hr = hp / 10, hc = hp - (hp / 10) * 10;
                if ((unsigned)(hr - r) < 7u && (unsigned)(hc - cl) < 7u)
                    v = Pf[px * 100 + hp];       // image-OOB taps are S=0 (k=0)
            }
            vals[n] = v; mx = fmaxf(mx, v);
        }
        mx = fmaxf(mx, __shfl_xor(mx, 1, 16));
        mx = fmaxf(mx, __shfl_xor(mx, 2, 16));
        mx = fmaxf(mx, __shfl_xor(mx, 4, 16));
        mx = fmaxf(mx, __shfl_xor(mx, 8, 16));
        float zs = 0.f;
        #pragma unroll
        for (int n = 0; n < 7; ++n) {
            const int hp = n * 16 + l16;
            const float ev = (vals[n] > -1.0e37f) ? __expf(vals[n] - mx) : 0.f;
            zs += ev;
            if (hp < 100) Pf[px * 100 + hp] = ev;
        }
        zs += __shfl_xor(zs, 1, 16);
        zs += __shfl_xor(zs, 2, 16);
        zs += __shfl_xor(zs, 4, 16);
        zs += __shfl_xor(zs, 8, 16);
        if (l16 == 0) rzL[px] = 1.0f / zs;
    }
    __syncthreads();                                           // B3

    // ---- PV (VALU, broadcast P) -> attB (own slice, no barrier needed) ----
    {
        const int cb = l16 * 8;
        float of[8];
        #pragma unroll
        for (int j = 0; j < 8; ++j) of[j] = 0.f;
        #pragma unroll
        for (int off = 0; off < 49; ++off) {
            const int di = off / 7, dj = off % 7;
            const int hp = (r + di) * 10 + cl + dj;
            const float ev = Pf[px * 100 + hp];
            short8 vv = *(const short8*)(halKV + hp * 136 + cb);
            #pragma unroll
            for (int j = 0; j < 8; ++j) of[j] += ev * bf2f((unsigned short)vv[j]);
        }
        const float rz = rzL[px];
        short8 ov;
        #pragma unroll
        for (int j = 0; j < 8; ++j) ov[j] = (short)f2bf(of[j] * rz);
        *(short8*)(attB + px * 136 + cb) = ov;
    }
    __syncthreads();                                           // B4

    // ---- final conv: 16px x 128och x K=256 (attB | xf regs) ----
    const int o0 = wv * 32;
    f32x4 fac[2];
    fac[0] = z4; fac[1] = z4;
    #pragma unroll
    for (int kk = 0; kk < 8; ++kk) {
        const int kbase = kk * 32 + g * 8;
        short8 av;
        if (kk < 4) av = *(const short8*)(attB + l16 * 136 + kbase);
        else        av = xf[kk - 4];
        #pragma unroll
        for (int nt = 0; nt < 2; ++nt) {
            short8 bv = *(const short8*)(ws + WO_OFF + (o0 + nt * 16 + l16) * 256 + kbase);
            fac[nt] = __builtin_amdgcn_mfma_f32_16x16x32_bf16(av, bv, fac[nt], 0, 0, 0);
        }
    }
    {
        const float* s  = sb + 10 * 128;
        const float* bb = sb + 11 * 128;
        #pragma unroll
        for (int nt = 0; nt < 2; ++nt) {
            const int o = o0 + nt * 16 + l16;
            const float sf = s[o], bf = bb[o];
            #pragma unroll
            for (int i = 0; i < 4; ++i)
                outT[o * 24 + g * 4 + i] = (short)f2bf(fac[nt][i] * sf + bf);  // no ReLU
        }
    }
    __syncthreads();                                           // B5
    #pragma unroll
    for (int pass = 0; pass < 2; ++pass) {
        const int u = tid + pass * 256;              // 512 units of 4 f32
        const int c = u >> 2, rr = u & 3;
        short4v sv = *(const short4v*)(outT + c * 24 + rr * 4);
        f32x4 fv;
        #pragma unroll
        for (int j = 0; j < 4; ++j) fv[j] = bf2f((unsigned short)sv[j]);
        *(f32x4*)(out + c * HW_PIX + (h0 + rr) * 128 + w0) = fv;
    }
}

extern "C" void kernel_launch(void* const* d_in, const int* in_sizes, int n_in,
                              void* d_out, int out_size, void* d_ws, size_t ws_size,
                              hipStream_t stream)
{
    const float* x = (const float*)d_in[0];
    short* ws = (short*)d_ws;

    CvtArgs ca;
    ca.w[0] = (const float*)d_in[1];   // w_q1
    ca.w[1] = (const float*)d_in[4];   // w_q2
    ca.w[2] = (const float*)d_in[7];   // w_k1
    ca.w[3] = (const float*)d_in[10];  // w_k2
    ca.w[4] = (const float*)d_in[13];  // w_v
    ca.w[5] = (const float*)d_in[16];  // w_o
    ca.sb[0]  = (const float*)d_in[2];  ca.sb[1]  = (const float*)d_in[3];
    ca.sb[2]  = (const float*)d_in[5];  ca.sb[3]  = (const float*)d_in[6];
    ca.sb[4]  = (const float*)d_in[8];  ca.sb[5]  = (const float*)d_in[9];
    ca.sb[6]  = (const float*)d_in[11]; ca.sb[7]  = (const float*)d_in[12];
    ca.sb[8]  = (const float*)d_in[14]; ca.sb[9]  = (const float*)d_in[15];
    ca.sb[10] = (const float*)d_in[17]; ca.sb[11] = (const float*)d_in[18];

    cvt_k<<<dim3(75), dim3(256), 0, stream>>>(ca, ws);
    qkv_k<<<dim3(1024), dim3(256), 0, stream>>>(x, ws);
    att_k<<<dim3(1024), dim3(256), 0, stream>>>(ws, (float*)d_out);
}